// Round 4
// baseline (505.336 us; speedup 1.0000x reference)
//
#include <hip/hip_runtime.h>
#include <math.h>

#define ROWS 18496          // bt*J*N = 64*17*17
#define SCALE 0.17677669529663687f  // 1/sqrt(32)

typedef unsigned short ushort_t;
typedef __attribute__((ext_vector_type(8))) short short8;
typedef __attribute__((ext_vector_type(4))) float f32x4;

__device__ __forceinline__ void fma4(float4& d, float s, const float4& v) {
    d.x = fmaf(s, v.x, d.x); d.y = fmaf(s, v.y, d.y);
    d.z = fmaf(s, v.z, d.z); d.w = fmaf(s, v.w, d.w);
}

__device__ __forceinline__ ushort_t f2bf(float x) {
    union { float f; unsigned u; } v; v.f = x;
    unsigned r = v.u + 0x7fffu + ((v.u >> 16) & 1u);
    return (ushort_t)(r >> 16);
}
__device__ __forceinline__ float bf2f(ushort_t b) {
    union { unsigned u; float f; } v; v.u = ((unsigned)b) << 16; return v.f;
}

__device__ __forceinline__ void gl_lds16(const void* g, void* l) {
    __builtin_amdgcn_global_load_lds(
        (const __attribute__((address_space(1))) void*)g,
        (__attribute__((address_space(3))) void*)l, 16, 0, 0);
}

// ---------------- merged conversion kernel ----------------------------
__global__ __launch_bounds__(256) void k_cvt_xw(
    const float4* __restrict__ x, ushort4* __restrict__ xhi, ushort4* __restrict__ xlo,
    const float* __restrict__ W, ushort_t* __restrict__ bh, ushort_t* __restrict__ bl)
{
    if (blockIdx.x < 4624) {
        int i = blockIdx.x * 256 + threadIdx.x;
        float4 v = x[i];
        ushort4 h, l;
        h.x = f2bf(v.x); l.x = f2bf(v.x - bf2f(h.x));
        h.y = f2bf(v.y); l.y = f2bf(v.y - bf2f(h.y));
        h.z = f2bf(v.z); l.z = f2bf(v.z - bf2f(h.z));
        h.w = f2bf(v.w); l.w = f2bf(v.w - bf2f(h.w));
        xhi[i] = h; xlo[i] = l;
    } else {
        int o = blockIdx.x - 4624;   // 0..1279
        int kk = threadIdx.x;        // 0..255
        int col = (o & 255) * 5 + (o >> 8);
        float v = W[(size_t)kk * 1280 + col];
        ushort_t hh = f2bf(v);
        bh[(size_t)o * 256 + kk] = hh;
        bl[(size_t)o * 256 + kk] = f2bf(v - bf2f(hh));
    }
}

// Wp (768x256 f32) -> transposed bf16 [n][k]
__global__ __launch_bounds__(256) void k_cvt_wp(
    const float* __restrict__ W, ushort_t* __restrict__ bh, ushort_t* __restrict__ bl)
{
    int n = blockIdx.x;          // 0..255
    for (int k = threadIdx.x; k < 768; k += 256) {
        float v = W[(size_t)k * 256 + n];
        ushort_t h = f2bf(v);
        bh[(size_t)n * 768 + k] = h;
        bl[(size_t)n * 768 + k] = f2bf(v - bf2f(h));
    }
}

// ---------------- split-bf16 MFMA GEMM --------------------------------
template<int BM, int BN, int K, int MODE>
__global__ __launch_bounds__(256) void k_gemm(
    const ushort_t* __restrict__ Ahi, const ushort_t* __restrict__ Alo,
    const ushort_t* __restrict__ Bhi, const ushort_t* __restrict__ Blo,
    const float* __restrict__ aux,
    float* __restrict__ out)
{
    constexpr int MT = BM / 32;
    constexpr int NT = BN / 32;
    __shared__ __attribute__((aligned(16))) ushort_t sAh[BM * 32];
    __shared__ __attribute__((aligned(16))) ushort_t sAl[BM * 32];
    __shared__ __attribute__((aligned(16))) ushort_t sBh[BN * 32];
    __shared__ __attribute__((aligned(16))) ushort_t sBl[BN * 32];

    const int t = threadIdx.x;
    const int lane = t & 63;
    const int ln = lane & 15, quad = lane >> 4;
    const int wave = t >> 6;
    const int wm = wave >> 1, wn = wave & 1;
    const int m0 = blockIdx.y * BM, n0 = blockIdx.x * BN;

    f32x4 acc[MT][NT];
#pragma unroll
    for (int i = 0; i < MT; ++i)
#pragma unroll
        for (int j = 0; j < NT; ++j) acc[i][j] = (f32x4){0.f, 0.f, 0.f, 0.f};

    for (int kb = 0; kb < K; kb += 32) {
        __syncthreads();
#pragma unroll
        for (int s = t; s < BM * 4; s += 256) {
            int row = s >> 2, kc = s & 3;
            int gr = m0 + row; if (gr > ROWS - 1) gr = ROWS - 1;
            size_t gb = ((size_t)gr * K + kb) * 2 + kc * 16;
            int lb = (s & ~63) * 16;
            gl_lds16((const char*)Ahi + gb, (char*)sAh + lb);
            gl_lds16((const char*)Alo + gb, (char*)sAl + lb);
        }
#pragma unroll
        for (int s = t; s < BN * 4; s += 256) {
            int row = s >> 2, kc = s & 3;
            size_t gb = ((size_t)(n0 + row) * K + kb) * 2 + kc * 16;
            int lb = (s & ~63) * 16;
            gl_lds16((const char*)Bhi + gb, (char*)sBh + lb);
            gl_lds16((const char*)Blo + gb, (char*)sBl + lb);
        }
        __syncthreads();

        short8 ah[MT], al[MT], bh[NT], bl[NT];
#pragma unroll
        for (int i = 0; i < MT; ++i) {
            int off = (wm * (BM / 2) + i * 16 + ln) * 32 + quad * 8;
            ah[i] = *(const short8*)&sAh[off];
            al[i] = *(const short8*)&sAl[off];
        }
#pragma unroll
        for (int j = 0; j < NT; ++j) {
            int off = (wn * (BN / 2) + j * 16 + ln) * 32 + quad * 8;
            bh[j] = *(const short8*)&sBh[off];
            bl[j] = *(const short8*)&sBl[off];
        }
#pragma unroll
        for (int i = 0; i < MT; ++i)
#pragma unroll
            for (int j = 0; j < NT; ++j) {
                acc[i][j] = __builtin_amdgcn_mfma_f32_16x16x32_bf16(ah[i], bh[j], acc[i][j], 0, 0, 0);
                acc[i][j] = __builtin_amdgcn_mfma_f32_16x16x32_bf16(ah[i], bl[j], acc[i][j], 0, 0, 0);
                acc[i][j] = __builtin_amdgcn_mfma_f32_16x16x32_bf16(al[i], bh[j], acc[i][j], 0, 0, 0);
            }
    }

#pragma unroll
    for (int i = 0; i < MT; ++i) {
#pragma unroll
        for (int r = 0; r < 4; ++r) {
            int gm = m0 + wm * (BM / 2) + i * 16 + quad * 4 + r;
            if (gm >= ROWS) continue;
            if (MODE == 0) {
                int jn = gm % 289;
                const float* Mrow = &aux[(size_t)jn * 256];
#pragma unroll
                for (int j = 0; j < NT; ++j) {
                    int gn = n0 + wn * (BN / 2) + j * 16 + ln;
                    out[(size_t)gm * 1280 + gn] = acc[i][j][r] * Mrow[gn & 255];
                }
            } else {
#pragma unroll
                for (int j = 0; j < NT; ++j) {
                    int gn = n0 + wn * (BN / 2) + j * 16 + ln;
                    out[(size_t)gm * 256 + gn] = acc[i][j][r] + aux[gn];
                }
            }
        }
    }
}

// ---------------- K2a v3: scores + 4 softmaxes -------------------------
// Block per (b,h), 320 threads. LDS: swizzled K tile + per-f output staging.
// Per f-phase: 153 tasks (i in 0..16, rc in 0..8 -> rows 2rc, 2rc+1), each
// computes 2 score rows + both softmaxes in registers, stores probs to LDS,
// then all 320 threads write out coalesced float4 (head/tail aligned).
__global__ __launch_bounds__(320) void k_scores3(
    const float* __restrict__ qkv5,
    const float* __restrict__ A_s, const float* __restrict__ A_v,
    const float* __restrict__ adjS, const float* __restrict__ adjV,
    float* __restrict__ attS, float* __restrict__ attV,
    float* __restrict__ attS2, float* __restrict__ attV2)
{
    __shared__ __attribute__((aligned(16))) float ksh[289 * 32];
    __shared__ __attribute__((aligned(16))) float outU[4913];
    __shared__ __attribute__((aligned(16))) float outB[4913];
    __shared__ float biasS[289];
    __shared__ float biasV[289];
    const int t  = threadIdx.x;
    const int bh = blockIdx.x;
    const int b  = bh >> 3, h = bh & 7;
    const size_t rowbase = (size_t)b * 289;

    // stage K tile (cols 256..511 of qkv5), chunk-swizzled
    for (int idx = t; idx < 2312; idx += 320) {
        int p = idx >> 3, c = idx & 7;
        float4 v = *(const float4*)&qkv5[(rowbase + p) * 1280 + 256 + h * 32 + c * 4];
        int cs = c ^ (p & 7);
        *(float4*)&ksh[p * 32 + cs * 4] = v;
    }
    for (int idx = t; idx < 578; idx += 320) {
        int f = idx / 289, rem = idx % 289;
        int jj = rem / 17, kk = rem % 17;
        if (f == 0)
            biasS[rem] = 0.5f * ((A_s[jj*17+kk] + adjS[jj*17+kk]) + (A_s[kk*17+jj] + adjS[kk*17+jj]));
        else
            biasV[rem] = 0.5f * ((A_v[jj*17+kk] + adjV[jj*17+kk]) + (A_v[kk*17+jj] + adjV[kk*17+jj]));
    }
    __syncthreads();

    const int head = (4 - (bh & 3)) & 3;          // floats to 16B-align bh*4913
    const int n4   = (4913 - head) >> 2;
    const int tail0 = head + n4 * 4;
    const int ntail = 4913 - tail0;

    for (int f = 0; f < 2; ++f) {
        if (t < 153) {
            const int i = t / 9, rc = t % 9;
            const int r0 = 2 * rc;
            const bool two = (rc < 8);
            const int r1 = two ? r0 + 1 : r0;
            const int pq0 = f ? (i * 17 + r0) : (r0 * 17 + i);
            const int pq1 = f ? (i * 17 + r1) : (r1 * 17 + i);

            float sc0[17], sc1[17];
#pragma unroll
            for (int kk = 0; kk < 17; ++kk) { sc0[kk] = 0.f; sc1[kk] = 0.f; }
#pragma unroll
            for (int c = 0; c < 8; ++c) {
                float4 q0 = *(const float4*)&qkv5[(rowbase + pq0) * 1280 + h * 32 + c * 4];
                float4 q1 = *(const float4*)&qkv5[(rowbase + pq1) * 1280 + h * 32 + c * 4];
#pragma unroll
                for (int kk = 0; kk < 17; ++kk) {
                    int pk = f ? (i * 17 + kk) : (kk * 17 + i);
                    float4 kv = *(const float4*)&ksh[pk * 32 + ((c ^ (pk & 7)) * 4)];
                    sc0[kk] = fmaf(q0.x, kv.x, sc0[kk]);
                    sc0[kk] = fmaf(q0.y, kv.y, sc0[kk]);
                    sc0[kk] = fmaf(q0.z, kv.z, sc0[kk]);
                    sc0[kk] = fmaf(q0.w, kv.w, sc0[kk]);
                    sc1[kk] = fmaf(q1.x, kv.x, sc1[kk]);
                    sc1[kk] = fmaf(q1.y, kv.y, sc1[kk]);
                    sc1[kk] = fmaf(q1.z, kv.z, sc1[kk]);
                    sc1[kk] = fmaf(q1.w, kv.w, sc1[kk]);
                }
            }
            const float* bias = f ? biasV : biasS;
            for (int rr = 0; rr < (two ? 2 : 1); ++rr) {
                const int row = r0 + rr;
                const float* sc = rr ? sc1 : sc0;
                int base = i * 289 + row * 17;
                float v[17];
#pragma unroll
                for (int kk = 0; kk < 17; ++kk) v[kk] = sc[kk] * SCALE;
                float mx = v[0];
#pragma unroll
                for (int kk = 1; kk < 17; ++kk) mx = fmaxf(mx, v[kk]);
                float e[17], sum = 0.f;
#pragma unroll
                for (int kk = 0; kk < 17; ++kk) { e[kk] = expf(v[kk] - mx); sum += e[kk]; }
                float inv = 1.f / sum;
#pragma unroll
                for (int kk = 0; kk < 17; ++kk) outU[base + kk] = e[kk] * inv;
#pragma unroll
                for (int kk = 0; kk < 17; ++kk) v[kk] += bias[row * 17 + kk];
                mx = v[0];
#pragma unroll
                for (int kk = 1; kk < 17; ++kk) mx = fmaxf(mx, v[kk]);
                sum = 0.f;
#pragma unroll
                for (int kk = 0; kk < 17; ++kk) { e[kk] = expf(v[kk] - mx); sum += e[kk]; }
                inv = 1.f / sum;
#pragma unroll
                for (int kk = 0; kk < 17; ++kk) outB[base + kk] = e[kk] * inv;
            }
        }
        __syncthreads();

        float* dstU = f ? attV : attS;
        float* dstB = f ? attV2 : attS2;
        const size_t baseg = (size_t)bh * 4913;
        for (int idx = t; idx < n4; idx += 320) {
            int o = head + idx * 4;
            float4 u, bb;
            u.x = outU[o]; u.y = outU[o+1]; u.z = outU[o+2]; u.w = outU[o+3];
            bb.x = outB[o]; bb.y = outB[o+1]; bb.z = outB[o+2]; bb.w = outB[o+3];
            *(float4*)&dstU[baseg + o] = u;
            *(float4*)&dstB[baseg + o] = bb;
        }
        if (t < head) { dstU[baseg + t] = outU[t]; dstB[baseg + t] = outB[t]; }
        else if (t - head < ntail) {
            int o = tail0 + (t - head);
            dstU[baseg + o] = outU[o]; dstB[baseg + o] = outB[o];
        }
        __syncthreads();
    }
}

__device__ __forceinline__ void store_hilo(ushort_t* yhi, ushort_t* ylo,
                                           size_t off, const float4& a)
{
    ushort4 h, l;
    h.x = f2bf(a.x); l.x = f2bf(a.x - bf2f(h.x));
    h.y = f2bf(a.y); l.y = f2bf(a.y - bf2f(h.y));
    h.z = f2bf(a.z); l.z = f2bf(a.z - bf2f(h.z));
    h.w = f2bf(a.w); l.w = f2bf(a.w - bf2f(h.w));
    *(ushort4*)&yhi[off] = h;
    *(ushort4*)&ylo[off] = l;
}

// ---------------- K2b: x_vs and x_vv -> y cols 256..767 (bf16 hi/lo) -----
__global__ __launch_bounds__(256) void k_xvs_xvv(
    const float* __restrict__ qkv5,
    const float* __restrict__ attS2, const float* __restrict__ attV2,
    ushort_t* __restrict__ yhi, ushort_t* __restrict__ ylo)
{
    __shared__ __attribute__((aligned(16))) float att2[4913];
    __shared__ __attribute__((aligned(16))) float vbuf[9248];
    const int t  = threadIdx.x;
    const int bh = blockIdx.x;
    const int b  = bh >> 3, h = bh & 7;
    const int pq = t >> 3, c4 = (t & 7) * 4;

    for (int idx = t; idx < 4913; idx += 256) att2[idx] = attS2[(size_t)bh * 4913 + idx];
    for (int idx = t; idx < 2312; idx += 256) {
        int p = idx >> 3, cc = (idx & 7) * 4;
        *(float4*)&vbuf[p * 32 + cc] =
            *(const float4*)&qkv5[(((size_t)b * 17 + p / 17) * 17 + p % 17) * 1280 + 512 + h * 32 + cc];
    }
    __syncthreads();
    for (int pi = 0; pi < 10; ++pi) {
        int p = pi * 32 + pq;
        if (p < 289) {
            int j = p / 17, n = p % 17;
            const float* arow = &att2[(n * 17 + j) * 17];
            float4 acc = {0,0,0,0};
            for (int kk = 0; kk < 17; ++kk) {
                float4 v = *(const float4*)&vbuf[(kk * 17 + n) * 32 + c4];
                fma4(acc, arow[kk], v);
            }
            size_t r = ((size_t)b * 17 + j) * 17 + n;
            store_hilo(yhi, ylo, r * 768 + 256 + h * 32 + c4, acc);
        }
    }
    __syncthreads();
    for (int idx = t; idx < 4913; idx += 256) att2[idx] = attV2[(size_t)bh * 4913 + idx];
    for (int idx = t; idx < 2312; idx += 256) {
        int p = idx >> 3, cc = (idx & 7) * 4;
        *(float4*)&vbuf[p * 32 + cc] =
            *(const float4*)&qkv5[(((size_t)b * 17 + p / 17) * 17 + p % 17) * 1280 + 768 + h * 32 + cc];
    }
    __syncthreads();
    for (int pi = 0; pi < 10; ++pi) {
        int p = pi * 32 + pq;
        if (p < 289) {
            int j = p / 17, n = p % 17;
            const float* arow = &att2[(j * 17 + n) * 17];
            float4 acc = {0,0,0,0};
            for (int mm = 0; mm < 17; ++mm) {
                float4 v = *(const float4*)&vbuf[(j * 17 + mm) * 32 + c4];
                fma4(acc, arow[mm], v);
            }
            size_t r = ((size_t)b * 17 + j) * 17 + n;
            store_hilo(yhi, ylo, r * 768 + 512 + h * 32 + c4, acc);
        }
    }
}

// ---------------- K2c v2: x_vsv, 5-point register tiling -----------------
// attS/attV staged in LDS; bV coeffs registered per point (5x17), v-row b128
// reads shared across 5 points -> 2x fewer LDS b128 than v1.
__global__ __launch_bounds__(256) void k_xvsv(
    const float* __restrict__ qkv5, const float* __restrict__ attS,
    const float* __restrict__ attV,
    ushort_t* __restrict__ yhi, ushort_t* __restrict__ ylo)
{
    __shared__ __attribute__((aligned(16))) float vbuf[9248];
    __shared__ __attribute__((aligned(16))) float aSsh[4913];
    __shared__ __attribute__((aligned(16))) float aVsh[4913];
    const int t  = threadIdx.x;
    const int bh = blockIdx.x;
    const int b  = bh >> 3, h = bh & 7;
    const int pq = t >> 3, c4 = (t & 7) * 4;

    for (int idx = t; idx < 2312; idx += 256) {
        int p = idx >> 3, cc = (idx & 7) * 4;
        *(float4*)&vbuf[p * 32 + cc] =
            *(const float4*)&qkv5[(((size_t)b * 17 + p / 17) * 17 + p % 17) * 1280 + 1024 + h * 32 + cc];
    }
    for (int idx = t; idx < 4913; idx += 256) {
        aSsh[idx] = attS[(size_t)bh * 4913 + idx];
        aVsh[idx] = attV[(size_t)bh * 4913 + idx];
    }
    __syncthreads();

    for (int pi = 0; pi < 2; ++pi) {
        int   aSb[5];
        bool  val[5];
        size_t rg[5];
        float bV[5][17];
#pragma unroll
        for (int g = 0; g < 5; ++g) {
            int p = pi * 160 + g * 32 + pq;
            val[g] = (p < 289);
            int pc = val[g] ? p : 288;
            int j = pc / 17, n = pc % 17;
            aSb[g] = (n * 17 + j) * 17;
            rg[g]  = ((size_t)b * 17 + j) * 17 + n;
            const float* bvrow = &aVsh[(j * 17 + n) * 17];
#pragma unroll
            for (int m = 0; m < 17; ++m) bV[g][m] = bvrow[m];
        }
        float4 acc[5];
#pragma unroll
        for (int g = 0; g < 5; ++g) acc[g] = (float4){0,0,0,0};

        for (int kk = 0; kk < 17; ++kk) {
            float a[5];
#pragma unroll
            for (int g = 0; g < 5; ++g) a[g] = aSsh[aSb[g] + kk];
            float4 tg[5];
#pragma unroll
            for (int g = 0; g < 5; ++g) tg[g] = (float4){0,0,0,0};
            const float* vrow = &vbuf[kk * 544 + c4];
#pragma unroll
            for (int m = 0; m < 17; ++m) {
                float4 v = *(const float4*)&vrow[m * 32];
#pragma unroll
                for (int g = 0; g < 5; ++g) fma4(tg[g], bV[g][m], v);
            }
#pragma unroll
            for (int g = 0; g < 5; ++g) fma4(acc[g], a[g], tg[g]);
        }
#pragma unroll
        for (int g = 0; g < 5; ++g)
            if (val[g]) store_hilo(yhi, ylo, rg[g] * 768 + h * 32 + c4, acc[g]);
    }
}

extern "C" void kernel_launch(void* const* d_in, const int* in_sizes, int n_in,
                              void* d_out, int out_size, void* d_ws, size_t ws_size,
                              hipStream_t stream)
{
    const float* x    = (const float*)d_in[0];
    const float* A_s  = (const float*)d_in[1];
    const float* A_v  = (const float*)d_in[2];
    const float* Wqkv = (const float*)d_in[3];
    const float* Wp   = (const float*)d_in[4];
    const float* bp   = (const float*)d_in[5];
    const float* M    = (const float*)d_in[6];
    const float* adjS = (const float*)d_in[7];
    const float* adjV = (const float*)d_in[8];
    float* out = (float*)d_out;

    char* w = (char*)d_ws;
    float*    qkv5  = (float*)w;
    ushort_t* wph   = (ushort_t*)w;                       // written after combines
    ushort_t* wpl   = (ushort_t*)(w + 393216);
    float* attS  = (float*)(w + 94699520);
    float* attV  = (float*)(w + 94699520 + 10061824);
    float* attS2 = (float*)(w + 94699520 + 2 * (size_t)10061824);
    float* attV2 = (float*)(w + 94699520 + 3 * (size_t)10061824);
    char* R = w + 134946816;
    ushort_t* xhi = (ushort_t*)R;
    ushort_t* xlo = (ushort_t*)(R + 9469952);
    ushort_t* wqh = (ushort_t*)(R + 18939904);
    ushort_t* wql = (ushort_t*)(R + 19595264);
    ushort_t* yhi = (ushort_t*)R;                         // alias (after k_gemm qkv done)
    ushort_t* ylo = (ushort_t*)(R + 28422144);

    k_cvt_xw<<<dim3(5904), 256, 0, stream>>>((const float4*)x, (ushort4*)xhi, (ushort4*)xlo,
                                             Wqkv, wqh, wql);
    k_gemm<128, 128, 256, 0><<<dim3(10, 145), 256, 0, stream>>>(xhi, xlo, wqh, wql, M, qkv5);
    k_scores3<<<dim3(512), 320, 0, stream>>>(qkv5, A_s, A_v, adjS, adjV,
                                             attS, attV, attS2, attV2);
    k_xvs_xvv<<<dim3(512), 256, 0, stream>>>(qkv5, attS2, attV2, yhi, ylo);
    k_xvsv<<<dim3(512), 256, 0, stream>>>(qkv5, attS, attV, yhi, ylo);
    k_cvt_wp<<<dim3(256), 256, 0, stream>>>(Wp, wph, wpl);
    k_gemm<128, 64, 768, 1><<<dim3(4, 145), 256, 0, stream>>>(yhi, ylo, wph, wpl, bp, out);
}

// Round 5
// 325.043 us; speedup vs baseline: 1.5547x; 1.5547x over previous
//
#include <hip/hip_runtime.h>
#include <math.h>

#define ROWS 18496          // bt*J*N = 64*17*17
#define SCALE 0.17677669529663687f  // 1/sqrt(32)

typedef unsigned short ushort_t;
typedef __attribute__((ext_vector_type(8))) short short8;
typedef __attribute__((ext_vector_type(4))) float f32x4;

__device__ __forceinline__ void fma4(float4& d, float s, const float4& v) {
    d.x = fmaf(s, v.x, d.x); d.y = fmaf(s, v.y, d.y);
    d.z = fmaf(s, v.z, d.z); d.w = fmaf(s, v.w, d.w);
}
__device__ __forceinline__ float dot4(const float4& a, const float4& b) {
    return a.x*b.x + a.y*b.y + a.z*b.z + a.w*b.w;
}

__device__ __forceinline__ ushort_t f2bf(float x) {
    union { float f; unsigned u; } v; v.f = x;
    unsigned r = v.u + 0x7fffu + ((v.u >> 16) & 1u);
    return (ushort_t)(r >> 16);
}
__device__ __forceinline__ float bf2f(ushort_t b) {
    union { unsigned u; float f; } v; v.u = ((unsigned)b) << 16; return v.f;
}

__device__ __forceinline__ void gl_lds16(const void* g, void* l) {
    __builtin_amdgcn_global_load_lds(
        (const __attribute__((address_space(1))) void*)g,
        (__attribute__((address_space(3))) void*)l, 16, 0, 0);
}

__device__ __forceinline__ void store_hilo(ushort_t* yhi, ushort_t* ylo,
                                           size_t off, const float4& a)
{
    ushort4 h, l;
    h.x = f2bf(a.x); l.x = f2bf(a.x - bf2f(h.x));
    h.y = f2bf(a.y); l.y = f2bf(a.y - bf2f(h.y));
    h.z = f2bf(a.z); l.z = f2bf(a.z - bf2f(h.z));
    h.w = f2bf(a.w); l.w = f2bf(a.w - bf2f(h.w));
    *(ushort4*)&yhi[off] = h;
    *(ushort4*)&ylo[off] = l;
}

// ---------------- merged conversion kernel ----------------------------
__global__ __launch_bounds__(256) void k_cvt_xw(
    const float4* __restrict__ x, ushort4* __restrict__ xhi, ushort4* __restrict__ xlo,
    const float* __restrict__ W, ushort_t* __restrict__ bh, ushort_t* __restrict__ bl)
{
    if (blockIdx.x < 4624) {
        int i = blockIdx.x * 256 + threadIdx.x;
        float4 v = x[i];
        ushort4 h, l;
        h.x = f2bf(v.x); l.x = f2bf(v.x - bf2f(h.x));
        h.y = f2bf(v.y); l.y = f2bf(v.y - bf2f(h.y));
        h.z = f2bf(v.z); l.z = f2bf(v.z - bf2f(h.z));
        h.w = f2bf(v.w); l.w = f2bf(v.w - bf2f(h.w));
        xhi[i] = h; xlo[i] = l;
    } else {
        int o = blockIdx.x - 4624;   // 0..1279
        int kk = threadIdx.x;        // 0..255
        int col = (o & 255) * 5 + (o >> 8);
        float v = W[(size_t)kk * 1280 + col];
        ushort_t hh = f2bf(v);
        bh[(size_t)o * 256 + kk] = hh;
        bl[(size_t)o * 256 + kk] = f2bf(v - bf2f(hh));
    }
}

// Wp (768x256 f32) -> transposed bf16 [n][k]
__global__ __launch_bounds__(256) void k_cvt_wp(
    const float* __restrict__ W, ushort_t* __restrict__ bh, ushort_t* __restrict__ bl)
{
    int n = blockIdx.x;          // 0..255
    for (int k = threadIdx.x; k < 768; k += 256) {
        float v = W[(size_t)k * 256 + n];
        ushort_t h = f2bf(v);
        bh[(size_t)n * 768 + k] = h;
        bl[(size_t)n * 768 + k] = f2bf(v - bf2f(h));
    }
}

// ---------------- split-bf16 MFMA GEMM --------------------------------
template<int BM, int BN, int K, int MODE>
__global__ __launch_bounds__(256) void k_gemm(
    const ushort_t* __restrict__ Ahi, const ushort_t* __restrict__ Alo,
    const ushort_t* __restrict__ Bhi, const ushort_t* __restrict__ Blo,
    const float* __restrict__ aux,
    float* __restrict__ out)
{
    constexpr int MT = BM / 32;
    constexpr int NT = BN / 32;
    __shared__ __attribute__((aligned(16))) ushort_t sAh[BM * 32];
    __shared__ __attribute__((aligned(16))) ushort_t sAl[BM * 32];
    __shared__ __attribute__((aligned(16))) ushort_t sBh[BN * 32];
    __shared__ __attribute__((aligned(16))) ushort_t sBl[BN * 32];

    const int t = threadIdx.x;
    const int lane = t & 63;
    const int ln = lane & 15, quad = lane >> 4;
    const int wave = t >> 6;
    const int wm = wave >> 1, wn = wave & 1;
    const int m0 = blockIdx.y * BM, n0 = blockIdx.x * BN;

    f32x4 acc[MT][NT];
#pragma unroll
    for (int i = 0; i < MT; ++i)
#pragma unroll
        for (int j = 0; j < NT; ++j) acc[i][j] = (f32x4){0.f, 0.f, 0.f, 0.f};

    for (int kb = 0; kb < K; kb += 32) {
        __syncthreads();
#pragma unroll
        for (int s = t; s < BM * 4; s += 256) {
            int row = s >> 2, kc = s & 3;
            int gr = m0 + row; if (gr > ROWS - 1) gr = ROWS - 1;
            size_t gb = ((size_t)gr * K + kb) * 2 + kc * 16;
            int lb = (s & ~63) * 16;
            gl_lds16((const char*)Ahi + gb, (char*)sAh + lb);
            gl_lds16((const char*)Alo + gb, (char*)sAl + lb);
        }
#pragma unroll
        for (int s = t; s < BN * 4; s += 256) {
            int row = s >> 2, kc = s & 3;
            size_t gb = ((size_t)(n0 + row) * K + kb) * 2 + kc * 16;
            int lb = (s & ~63) * 16;
            gl_lds16((const char*)Bhi + gb, (char*)sBh + lb);
            gl_lds16((const char*)Blo + gb, (char*)sBl + lb);
        }
        __syncthreads();

        short8 ah[MT], al[MT], bh[NT], bl[NT];
#pragma unroll
        for (int i = 0; i < MT; ++i) {
            int off = (wm * (BM / 2) + i * 16 + ln) * 32 + quad * 8;
            ah[i] = *(const short8*)&sAh[off];
            al[i] = *(const short8*)&sAl[off];
        }
#pragma unroll
        for (int j = 0; j < NT; ++j) {
            int off = (wn * (BN / 2) + j * 16 + ln) * 32 + quad * 8;
            bh[j] = *(const short8*)&sBh[off];
            bl[j] = *(const short8*)&sBl[off];
        }
#pragma unroll
        for (int i = 0; i < MT; ++i)
#pragma unroll
            for (int j = 0; j < NT; ++j) {
                acc[i][j] = __builtin_amdgcn_mfma_f32_16x16x32_bf16(ah[i], bh[j], acc[i][j], 0, 0, 0);
                acc[i][j] = __builtin_amdgcn_mfma_f32_16x16x32_bf16(ah[i], bl[j], acc[i][j], 0, 0, 0);
                acc[i][j] = __builtin_amdgcn_mfma_f32_16x16x32_bf16(al[i], bh[j], acc[i][j], 0, 0, 0);
            }
    }

#pragma unroll
    for (int i = 0; i < MT; ++i) {
#pragma unroll
        for (int r = 0; r < 4; ++r) {
            int gm = m0 + wm * (BM / 2) + i * 16 + quad * 4 + r;
            if (gm >= ROWS) continue;
            if (MODE == 0) {
                int jn = gm % 289;
                const float* Mrow = &aux[(size_t)jn * 256];
#pragma unroll
                for (int j = 0; j < NT; ++j) {
                    int gn = n0 + wn * (BN / 2) + j * 16 + ln;
                    out[(size_t)gm * 1280 + gn] = acc[i][j][r] * Mrow[gn & 255];
                }
            } else {
#pragma unroll
                for (int j = 0; j < NT; ++j) {
                    int gn = n0 + wn * (BN / 2) + j * 16 + ln;
                    out[(size_t)gm * 256 + gn] = acc[i][j][r] + aux[gn];
                }
            }
        }
    }
}

// ---------------- fused attention: scores + softmaxes + all combines -----
// Block per (b,h), 320 threads, 63.2 KB LDS -> 2 blocks/CU, grid 512 = all
// resident. Probs never leave LDS. Biased softmax derived exactly via
// softmax(raw+bias) = normalize(softmax(raw) * exp(bias)).
// LDS: aS[4913]=[n][j][k], aV[4913]=[j][n][m], ebS[289], ebV[289],
//      buf[289*20] (16 cols used per channel-half pass; pad 20 = 16B-aligned,
//      bank-spread rows).
__global__ __launch_bounds__(320) void k_att(
    const float* __restrict__ qkv5,
    const float* __restrict__ A_s, const float* __restrict__ A_v,
    const float* __restrict__ adjS, const float* __restrict__ adjV,
    ushort_t* __restrict__ yhi, ushort_t* __restrict__ ylo)
{
    __shared__ __attribute__((aligned(16))) float sm[16184];
    float* aS  = sm;            // 4913
    float* aV  = sm + 4913;     // 4913
    float* ebS = sm + 9826;     // 289
    float* ebV = sm + 10115;    // 289
    float* buf = sm + 10404;    // 289*20

    const int t  = threadIdx.x;
    const int bh = blockIdx.x;
    const int b  = bh >> 3, h = bh & 7;
    const size_t rowbase = (size_t)b * 289;

    // ---- P0: exp of symmetrized biases ----
    for (int idx = t; idx < 578; idx += 320) {
        int f = idx / 289, rem = idx % 289;
        int jj = rem / 17, kk = rem % 17;
        float bias;
        if (f == 0)
            bias = 0.5f * ((A_s[jj*17+kk] + adjS[jj*17+kk]) + (A_s[kk*17+jj] + adjS[kk*17+jj]));
        else
            bias = 0.5f * ((A_v[jj*17+kk] + adjV[jj*17+kk]) + (A_v[kk*17+jj] + adjV[kk*17+jj]));
        (f ? ebV : ebS)[rem] = expf(bias);
    }

    // ---- P1: raw scores (both S and V), channel-halved k-tile ----
    float accS[17], accV[17];
#pragma unroll
    for (int i = 0; i < 17; ++i) { accS[i] = 0.f; accV[i] = 0.f; }
    const bool val = (t < 289);
    const int a = t / 17, bb = t % 17;   // q row = a*17+bb = t; S: n=bb,j=a; V: j=a,n=bb
    for (int ch = 0; ch < 2; ++ch) {
        __syncthreads();
        for (int idx = t; idx < 1156; idx += 320) {
            int p = idx >> 2, c = idx & 3;
            *(float4*)&buf[p * 20 + c * 4] =
                *(const float4*)&qkv5[(rowbase + p) * 1280 + 256 + h * 32 + ch * 16 + c * 4];
        }
        __syncthreads();
        if (val) {
            const float* qp = &qkv5[(rowbase + t) * 1280 + h * 32 + ch * 16];
            float4 q0 = *(const float4*)&qp[0];
            float4 q1 = *(const float4*)&qp[4];
            float4 q2 = *(const float4*)&qp[8];
            float4 q3 = *(const float4*)&qp[12];
#pragma unroll
            for (int kk = 0; kk < 17; ++kk) {
                const float4* r = (const float4*)&buf[(kk * 17 + bb) * 20];
                accS[kk] += dot4(q0, r[0]) + dot4(q1, r[1]) + dot4(q2, r[2]) + dot4(q3, r[3]);
            }
#pragma unroll
            for (int mm = 0; mm < 17; ++mm) {
                const float4* r = (const float4*)&buf[(a * 17 + mm) * 20];
                accV[mm] += dot4(q0, r[0]) + dot4(q1, r[1]) + dot4(q2, r[2]) + dot4(q3, r[3]);
            }
        }
    }
    if (val) {
#pragma unroll
        for (int kk = 0; kk < 17; ++kk) aS[bb * 289 + a * 17 + kk] = accS[kk] * SCALE;
#pragma unroll
        for (int mm = 0; mm < 17; ++mm) aV[a * 289 + bb * 17 + mm] = accV[mm] * SCALE;
    }
    __syncthreads();

    // ---- P2: in-place unbiased softmax on all 578 rows ----
    for (int idx = t; idx < 578; idx += 320) {
        float* row = (idx < 289) ? &aS[idx * 17] : &aV[(idx - 289) * 17];
        float v[17];
#pragma unroll
        for (int kk = 0; kk < 17; ++kk) v[kk] = row[kk];
        float mx = v[0];
#pragma unroll
        for (int kk = 1; kk < 17; ++kk) mx = fmaxf(mx, v[kk]);
        float sum = 0.f;
#pragma unroll
        for (int kk = 0; kk < 17; ++kk) { v[kk] = expf(v[kk] - mx); sum += v[kk]; }
        float inv = 1.f / sum;
#pragma unroll
        for (int kk = 0; kk < 17; ++kk) row[kk] = v[kk] * inv;
    }
    // (no sync needed: P3's staging sync orders P2 before consumers)

    // ---- P3: x_vsv -> y cols 0..255. 4 points/thread share all row reads --
    for (int ch = 0; ch < 2; ++ch) {
        __syncthreads();
        for (int idx = t; idx < 1156; idx += 320) {
            int p = idx >> 2, c = idx & 3;
            *(float4*)&buf[p * 20 + c * 4] =
                *(const float4*)&qkv5[(rowbase + p) * 1280 + 1024 + h * 32 + ch * 16 + c * 4];
        }
        __syncthreads();
        if (t < 292) {
            const int c4 = (t & 3) * 4;
            const int pb = (t >> 2) * 4;          // 0..288 step 4
            const int nv = (289 - pb < 4) ? (289 - pb) : 4;
            int jj[4], nn[4];
            float eV[4][17];
#pragma unroll
            for (int g = 0; g < 4; ++g) {
                int p = pb + g; if (p > 288) p = 288;
                jj[g] = p / 17; nn[g] = p % 17;
                const float* src = &aV[jj[g] * 289 + nn[g] * 17];
#pragma unroll
                for (int m = 0; m < 17; ++m) eV[g][m] = src[m];
            }
            float4 acc[4];
#pragma unroll
            for (int g = 0; g < 4; ++g) acc[g] = (float4){0,0,0,0};
            for (int kk = 0; kk < 17; ++kk) {
                float4 tg[4];
#pragma unroll
                for (int g = 0; g < 4; ++g) tg[g] = (float4){0,0,0,0};
#pragma unroll
                for (int m = 0; m < 17; ++m) {
                    float4 v = *(const float4*)&buf[(kk * 17 + m) * 20 + c4];
#pragma unroll
                    for (int g = 0; g < 4; ++g) fma4(tg[g], eV[g][m], v);
                }
#pragma unroll
                for (int g = 0; g < 4; ++g) {
                    float es = aS[nn[g] * 289 + jj[g] * 17 + kk];
                    fma4(acc[g], es, tg[g]);
                }
            }
            for (int g = 0; g < nv; ++g) {
                size_t rowg = rowbase + pb + g;
                store_hilo(yhi, ylo, rowg * 768 + h * 32 + ch * 16 + c4, acc[g]);
            }
        }
    }

    // ---- P4: x_vs (aS2 = normalize(aS*ebS)) -> y cols 256..511 ----------
    for (int ch = 0; ch < 2; ++ch) {
        __syncthreads();
        for (int idx = t; idx < 1156; idx += 320) {
            int p = idx >> 2, c = idx & 3;
            *(float4*)&buf[p * 20 + c * 4] =
                *(const float4*)&qkv5[(rowbase + p) * 1280 + 512 + h * 32 + ch * 16 + c * 4];
        }
        __syncthreads();
        for (int u = t; u < 612; u += 320) {
            int c4 = (u & 3) * 4, rest = u >> 2;      // rest 0..152
            int n = rest % 17, jp = rest / 17;        // jp 0..8
            int j0 = jp * 2;
            int nj = (j0 == 16) ? 1 : 2;
            int j1 = (j0 + 1 > 16) ? 16 : j0 + 1;
            float w0[17], w1[17];
            float s0 = 0.f, s1 = 0.f;
            const float* as0 = &aS[n * 289 + j0 * 17];
            const float* as1 = &aS[n * 289 + j1 * 17];
            const float* eb0 = &ebS[j0 * 17];
            const float* eb1 = &ebS[j1 * 17];
#pragma unroll
            for (int kk = 0; kk < 17; ++kk) {
                w0[kk] = as0[kk] * eb0[kk]; s0 += w0[kk];
                w1[kk] = as1[kk] * eb1[kk]; s1 += w1[kk];
            }
            float i0 = 1.f / s0, i1 = 1.f / s1;
            float4 a0 = {0,0,0,0}, a1 = {0,0,0,0};
            for (int kk = 0; kk < 17; ++kk) {
                float4 v = *(const float4*)&buf[(kk * 17 + n) * 20 + c4];
                fma4(a0, w0[kk], v);
                fma4(a1, w1[kk], v);
            }
            a0.x *= i0; a0.y *= i0; a0.z *= i0; a0.w *= i0;
            a1.x *= i1; a1.y *= i1; a1.z *= i1; a1.w *= i1;
            size_t r0 = rowbase + j0 * 17 + n;
            store_hilo(yhi, ylo, r0 * 768 + 256 + h * 32 + ch * 16 + c4, a0);
            if (nj == 2) {
                size_t r1 = rowbase + j1 * 17 + n;
                store_hilo(yhi, ylo, r1 * 768 + 256 + h * 32 + ch * 16 + c4, a1);
            }
        }
    }

    // ---- P5: x_vv (aV2 = normalize(aV*ebV)) -> y cols 512..767 ----------
    for (int ch = 0; ch < 2; ++ch) {
        __syncthreads();
        for (int idx = t; idx < 1156; idx += 320) {
            int p = idx >> 2, c = idx & 3;
            *(float4*)&buf[p * 20 + c * 4] =
                *(const float4*)&qkv5[(rowbase + p) * 1280 + 768 + h * 32 + ch * 16 + c * 4];
        }
        __syncthreads();
        for (int u = t; u < 612; u += 320) {
            int c4 = (u & 3) * 4, rest = u >> 2;
            int j = rest % 17, np = rest / 17;        // np 0..8
            int n0 = np * 2;
            int nn = (n0 == 16) ? 1 : 2;
            int n1 = (n0 + 1 > 16) ? 16 : n0 + 1;
            float w0[17], w1[17];
            float s0 = 0.f, s1 = 0.f;
            const float* av0 = &aV[j * 289 + n0 * 17];
            const float* av1 = &aV[j * 289 + n1 * 17];
            const float* eb0 = &ebV[n0 * 17];
            const float* eb1 = &ebV[n1 * 17];
#pragma unroll
            for (int mm = 0; mm < 17; ++mm) {
                w0[mm] = av0[mm] * eb0[mm]; s0 += w0[mm];
                w1[mm] = av1[mm] * eb1[mm]; s1 += w1[mm];
            }
            float i0 = 1.f / s0, i1 = 1.f / s1;
            float4 a0 = {0,0,0,0}, a1 = {0,0,0,0};
            for (int mm = 0; mm < 17; ++mm) {
                float4 v = *(const float4*)&buf[(j * 17 + mm) * 20 + c4];
                fma4(a0, w0[mm], v);
                fma4(a1, w1[mm], v);
            }
            a0.x *= i0; a0.y *= i0; a0.z *= i0; a0.w *= i0;
            a1.x *= i1; a1.y *= i1; a1.z *= i1; a1.w *= i1;
            size_t r0 = rowbase + j * 17 + n0;
            store_hilo(yhi, ylo, r0 * 768 + 512 + h * 32 + ch * 16 + c4, a0);
            if (nn == 2) {
                size_t r1 = rowbase + j * 17 + n1;
                store_hilo(yhi, ylo, r1 * 768 + 512 + h * 32 + ch * 16 + c4, a1);
            }
        }
    }
}

extern "C" void kernel_launch(void* const* d_in, const int* in_sizes, int n_in,
                              void* d_out, int out_size, void* d_ws, size_t ws_size,
                              hipStream_t stream)
{
    const float* x    = (const float*)d_in[0];
    const float* A_s  = (const float*)d_in[1];
    const float* A_v  = (const float*)d_in[2];
    const float* Wqkv = (const float*)d_in[3];
    const float* Wp   = (const float*)d_in[4];
    const float* bp   = (const float*)d_in[5];
    const float* M    = (const float*)d_in[6];
    const float* adjS = (const float*)d_in[7];
    const float* adjV = (const float*)d_in[8];
    float* out = (float*)d_out;

    char* w = (char*)d_ws;
    float*    qkv5  = (float*)w;                          // 95 MB, dead after k_att
    ushort_t* wph   = (ushort_t*)w;                       // written after k_att
    ushort_t* wpl   = (ushort_t*)(w + 393216);
    char* R = w + 134946816;
    ushort_t* xhi = (ushort_t*)R;
    ushort_t* xlo = (ushort_t*)(R + 9469952);
    ushort_t* wqh = (ushort_t*)(R + 18939904);
    ushort_t* wql = (ushort_t*)(R + 19595264);
    ushort_t* yhi = (ushort_t*)R;                         // alias (after qkv gemm done)
    ushort_t* ylo = (ushort_t*)(R + 28422144);

    k_cvt_xw<<<dim3(5904), 256, 0, stream>>>((const float4*)x, (ushort4*)xhi, (ushort4*)xlo,
                                             Wqkv, wqh, wql);
    k_gemm<128, 128, 256, 0><<<dim3(10, 145), 256, 0, stream>>>(xhi, xlo, wqh, wql, M, qkv5);
    k_att<<<dim3(512), 320, 0, stream>>>(qkv5, A_s, A_v, adjS, adjV, yhi, ylo);
    k_cvt_wp<<<dim3(256), 256, 0, stream>>>(Wp, wph, wpl);
    k_gemm<128, 64, 768, 1><<<dim3(4, 145), 256, 0, stream>>>(yhi, ylo, wph, wpl, bp, out);
}